// Round 1
// baseline (974.586 us; speedup 1.0000x reference)
//
#include <hip/hip_runtime.h>
#include <math.h>

#define NB 2048
#define NV 110
#define NH1 5
#define NF1 24
#define NH2 3
#define NF2 3
#define C1 (NH1*NF1)   // 120
#define NEGV -9e15f
#define LALPHA 0.2f

constexpr int NN = NV*NV;          // 12100
constexpr int T1 = 512;
constexpr int T2 = 512;

__device__ __forceinline__ float lrelu(float x){ return x > 0.f ? x : LALPHA*x; }
__device__ __forceinline__ float sigm(float x){ return 1.f/(1.f+__expf(-x)); }
__device__ __forceinline__ float wmax(float v){
  #pragma unroll
  for (int d=32; d; d>>=1) v = fmaxf(v, __shfl_xor(v,d));
  return v;
}
__device__ __forceinline__ float wsum(float v){
  #pragma unroll
  for (int d=32; d; d>>=1) v += __shfl_xor(v,d);
  return v;
}

// ---------------- Kernel 1: mask-gate + GAT layer 1 (concat) ----------------
__global__ __launch_bounds__(T1) void gat1_kernel(
  const float* __restrict__ X, const float* __restrict__ A,
  const float* __restrict__ M, const float* __restrict__ W1,
  const float* __restrict__ as1, const float* __restrict__ an1,
  const float* __restrict__ b1,
  float* __restrict__ h1, unsigned long long* __restrict__ amask)
{
  __shared__ float sXA[NN];            // Xm, later attn buffer 0   (48400 B)
  __shared__ float sF[NH1*NV*NF1];     // feats                      (52800 B)
  __shared__ float sW[NH1*NV*NF1];     // W1, later attn buffer 1    (52800 B)
  __shared__ float sES[NH1*NV];        // (2200 B)
  __shared__ float sEN[NH1*NV];        // (2200 B)
  __shared__ unsigned long long sAM[NV*2]; // (1760 B)  total = 160160 B

  const int b = blockIdx.x, tid = threadIdx.x;
  const int wave = tid >> 6, lane = tid & 63;
  const float* __restrict__ Xb = X + (size_t)b*NN;
  const float* __restrict__ Ab = A + (size_t)b*NN;

  // stage Xm = X*sigmoid(M), stage W1, build adjacency bitmask
  for (int i = tid; i < NN; i += T1)
    sXA[i] = Xb[i] * sigm(M[i]);
  for (int i = tid; i < NH1*NV*NF1; i += T1)
    sW[i] = W1[i];
  for (int n = wave; n < NV; n += T1/64) {
    unsigned long long m0 = __ballot(Ab[n*NV + lane] > 0.f);
    int mm = 64 + lane;
    unsigned long long m1 = __ballot((mm < NV) && (Ab[n*NV + mm] > 0.f));
    if (lane == 0) {
      sAM[2*n] = m0; sAM[2*n+1] = m1;
      amask[(size_t)b*2*NV + 2*n]     = m0;
      amask[(size_t)b*2*NV + 2*n + 1] = m1;
    }
  }
  __syncthreads();

  // feats[h][n][f] = sum_i Xm[n][i] * W1[h][i][f]   (tiles: 2 rows x 8 cols)
  for (int t = tid; t < NH1*55*3; t += T1) {
    const int h = t/165, r = t%165, np = r/3, ft = r%3;
    const int n0 = np*2, f0 = ft*8;
    float a0[8] = {0,0,0,0,0,0,0,0};
    float a1[8] = {0,0,0,0,0,0,0,0};
    const float* wb = &sW[h*NV*NF1 + f0];
    const float* x0 = &sXA[n0*NV];
    const float* x1 = x0 + NV;
    for (int i = 0; i < NV; ++i) {
      const float xa = x0[i], xb = x1[i];
      const float4 wA = *(const float4*)(wb + i*NF1);
      const float4 wB = *(const float4*)(wb + i*NF1 + 4);
      a0[0]+=xa*wA.x; a0[1]+=xa*wA.y; a0[2]+=xa*wA.z; a0[3]+=xa*wA.w;
      a0[4]+=xa*wB.x; a0[5]+=xa*wB.y; a0[6]+=xa*wB.z; a0[7]+=xa*wB.w;
      a1[0]+=xb*wA.x; a1[1]+=xb*wA.y; a1[2]+=xb*wA.z; a1[3]+=xb*wA.w;
      a1[4]+=xb*wB.x; a1[5]+=xb*wB.y; a1[6]+=xb*wB.z; a1[7]+=xb*wB.w;
    }
    float* d0 = &sF[(h*NV + n0)*NF1 + f0];
    #pragma unroll
    for (int j = 0; j < 8; ++j) d0[j] = a0[j];
    #pragma unroll
    for (int j = 0; j < 8; ++j) d0[NF1 + j] = a1[j];
  }
  __syncthreads();

  // attention logits per node
  for (int t = tid; t < NH1*NV; t += T1) {
    const int h = t/NV, n = t%NV;
    const float* f = &sF[(h*NV + n)*NF1];
    float es = 0.f, en = 0.f;
    #pragma unroll
    for (int j = 0; j < NF1; ++j) {
      es += f[j]*as1[h*NF1+j];
      en += f[j]*an1[h*NF1+j];
    }
    sES[t] = es; sEN[t] = en;
  }
  __syncthreads();

  float* attnb0 = sXA;   // Xm dead after feats phase
  float* attnb1 = sW;    // W1 dead after feats phase
  for (int pass = 0; pass < 3; ++pass) {
    const int hA = pass*2;
    const int nh = (hA+1 < NH1) ? 2 : 1;
    // masked row softmax (one wave per row)
    for (int rr = wave; rr < nh*NV; rr += T1/64) {
      const int hh = rr / NV, n = rr % NV;
      const int h = hA + hh;
      float* ab = hh ? attnb1 : attnb0;
      const float esv = sES[h*NV + n];
      const unsigned long long am0 = sAM[2*n], am1 = sAM[2*n+1];
      float v0 = lrelu(esv + sEN[h*NV + lane]);
      if (!((am0 >> lane) & 1ull)) v0 = NEGV;
      const int mm = 64 + lane;
      float v1 = NEGV;
      if (mm < NV) {
        v1 = lrelu(esv + sEN[h*NV + mm]);
        if (!((am1 >> lane) & 1ull)) v1 = NEGV;
      }
      const float mx = wmax(fmaxf(v0, v1));
      const float p0 = __expf(v0 - mx);
      const float p1 = (mm < NV) ? __expf(v1 - mx) : 0.f;
      const float inv = 1.f / wsum(p0 + p1);
      ab[n*NV + lane] = p0 * inv;
      if (mm < NV) ab[n*NV + mm] = p1 * inv;
    }
    __syncthreads();
    // h1[n][h*24+f] = lrelu(sum_m attn[n][m]*feats[h][m][f] + b1[f])
    for (int t = tid; t < nh*165; t += T1) {
      const int hh = t/165, r = t%165, np = r/3, ft = r%3;
      const int h = hA + hh, n0 = np*2, f0 = ft*8;
      const float* ab = hh ? attnb1 : attnb0;
      float a0[8] = {0,0,0,0,0,0,0,0};
      float a1[8] = {0,0,0,0,0,0,0,0};
      const float* p0r = &ab[n0*NV];
      const float* p1r = p0r + NV;
      const float* fb = &sF[h*NV*NF1 + f0];
      for (int m = 0; m < NV; ++m) {
        const float pa = p0r[m], pb = p1r[m];
        const float4 fA = *(const float4*)(fb + m*NF1);
        const float4 fB = *(const float4*)(fb + m*NF1 + 4);
        a0[0]+=pa*fA.x; a0[1]+=pa*fA.y; a0[2]+=pa*fA.z; a0[3]+=pa*fA.w;
        a0[4]+=pa*fB.x; a0[5]+=pa*fB.y; a0[6]+=pa*fB.z; a0[7]+=pa*fB.w;
        a1[0]+=pb*fA.x; a1[1]+=pb*fA.y; a1[2]+=pb*fA.z; a1[3]+=pb*fA.w;
        a1[4]+=pb*fB.x; a1[5]+=pb*fB.y; a1[6]+=pb*fB.z; a1[7]+=pb*fB.w;
      }
      float* o0 = &h1[((size_t)b*NV + n0)*C1 + h*NF1 + f0];
      #pragma unroll
      for (int j = 0; j < 8; ++j) {
        const float bv = b1[f0+j];
        o0[j]      = lrelu(a0[j] + bv);
        o0[C1 + j] = lrelu(a1[j] + bv);
      }
    }
    __syncthreads();
  }
}

// ------------- Kernel 2: GAT layer 2 (average) + heads + readout -------------
__global__ __launch_bounds__(T2) void gat2_kernel(
  const float* __restrict__ h1, const unsigned long long* __restrict__ amask,
  const float* __restrict__ W2, const float* __restrict__ as2,
  const float* __restrict__ an2, const float* __restrict__ b2,
  const float* __restrict__ fc1w, const float* __restrict__ fc2w,
  float* __restrict__ out)
{
  __shared__ float sH[NV*C1];        // h1 staged, later attn buf (12100<=13200)
  __shared__ float sW2[NH2*NF2*C1];  // W2 transposed [g][f2][c]
  __shared__ float sF2[NH2*NF2*NV];  // feats2 [g][f2][n]
  __shared__ float sES[NH2*NV], sEN[NH2*NV];
  __shared__ float sHS[NV*NF2];      // head-sum accumulator
  __shared__ float sT[NV];
  __shared__ float sS[NV];
  __shared__ unsigned long long sAM[NV*2];

  const int b = blockIdx.x, tid = threadIdx.x;
  const int wave = tid >> 6, lane = tid & 63;

  for (int i = tid; i < NV*C1; i += T2) sH[i] = h1[(size_t)b*NV*C1 + i];
  for (int i = tid; i < NH2*C1*NF2; i += T2) {
    const int g = i/(C1*NF2), r = i%(C1*NF2), c = r/NF2, f2 = r%NF2;
    sW2[(g*NF2 + f2)*C1 + c] = W2[i];
  }
  for (int i = tid; i < 2*NV; i += T2) sAM[i] = amask[(size_t)b*2*NV + i];
  for (int i = tid; i < NV*NF2; i += T2) sHS[i] = 0.f;
  __syncthreads();

  // feats2[g][f2][n] = sum_c h1[n][c] * W2[g][c][f2]
  for (int t = tid; t < NV*NH2*NF2; t += T2) {
    const int n = t/(NH2*NF2), r = t%(NH2*NF2), g = r/NF2, f2 = r%NF2;
    const float* hr = &sH[n*C1];
    const float* wr = &sW2[(g*NF2 + f2)*C1];
    float acc = 0.f;
    for (int c = 0; c < C1; c += 4) {
      const float4 hv = *(const float4*)(hr + c);
      const float4 wv = *(const float4*)(wr + c);
      acc += hv.x*wv.x + hv.y*wv.y + hv.z*wv.z + hv.w*wv.w;
    }
    sF2[(g*NF2 + f2)*NV + n] = acc;
  }
  __syncthreads();

  for (int t = tid; t < NH2*NV; t += T2) {
    const int g = t/NV, n = t%NV;
    float es = 0.f, en = 0.f;
    #pragma unroll
    for (int f2 = 0; f2 < NF2; ++f2) {
      const float v = sF2[(g*NF2 + f2)*NV + n];
      es += v*as2[g*NF2+f2];
      en += v*an2[g*NF2+f2];
    }
    sES[t] = es; sEN[t] = en;
  }
  __syncthreads();

  float* attn = sH;   // h1 staging dead after feats2
  for (int g = 0; g < NH2; ++g) {
    for (int n = wave; n < NV; n += T2/64) {
      const float esv = sES[g*NV+n];
      const unsigned long long am0 = sAM[2*n], am1 = sAM[2*n+1];
      float v0 = lrelu(esv + sEN[g*NV + lane]);
      if (!((am0>>lane)&1ull)) v0 = NEGV;
      const int mm = 64+lane;
      float v1 = NEGV;
      if (mm < NV) {
        v1 = lrelu(esv + sEN[g*NV+mm]);
        if (!((am1>>lane)&1ull)) v1 = NEGV;
      }
      const float mx = wmax(fmaxf(v0,v1));
      const float p0 = __expf(v0-mx);
      const float p1 = (mm<NV)? __expf(v1-mx) : 0.f;
      const float inv = 1.f/wsum(p0+p1);
      attn[n*NV+lane] = p0*inv;
      if (mm<NV) attn[n*NV+mm] = p1*inv;
    }
    __syncthreads();
    if (tid < NV*NF2) {
      const int n = tid/NF2, f2 = tid%NF2;
      const float* ar = &attn[n*NV];
      const float* fr = &sF2[(g*NF2+f2)*NV];
      float acc = 0.f;
      for (int m = 0; m < NV; ++m) acc += ar[m]*fr[m];
      sHS[tid] += acc;
    }
    __syncthreads();
  }

  // t[n] = sigmoid( lrelu(mean_g + b2) . fc1 )
  if (tid < NV) {
    float dot = 0.f;
    #pragma unroll
    for (int f2 = 0; f2 < NF2; ++f2) {
      const float h2v = lrelu(sHS[tid*NF2+f2]*(1.f/NH2) + b2[f2]);
      dot += h2v*fc1w[f2];
    }
    sT[tid] = sigm(dot);
  }
  __syncthreads();
  // s[m] = sum_i t[i]*fc2[i][m]
  if (tid < NV) {
    float acc = 0.f;
    for (int i = 0; i < NV; ++i) acc += sT[i]*fc2w[i*NV + tid];
    sS[tid] = acc;
  }
  __syncthreads();
  // out[b] = sum_m t[m]*softmax(s)[m]
  if (wave == 0) {
    const float s0 = sS[lane];
    const float s1 = (64+lane < NV) ? sS[64+lane] : -1e38f;
    const float mx = wmax(fmaxf(s0,s1));
    const float p0 = __expf(s0-mx);
    const float p1 = (64+lane < NV) ? __expf(s1-mx) : 0.f;
    const float sum = wsum(p0+p1);
    float val = sT[lane]*p0 + ((64+lane<NV)? sT[64+lane]*p1 : 0.f);
    val = wsum(val);
    if (lane == 0) out[b] = val/sum;
  }
}

extern "C" void kernel_launch(void* const* d_in, const int* in_sizes, int n_in,
                              void* d_out, int out_size, void* d_ws, size_t ws_size,
                              hipStream_t stream) {
  const float* X   = (const float*)d_in[0];
  const float* A   = (const float*)d_in[1];
  const float* M   = (const float*)d_in[2];
  const float* W1  = (const float*)d_in[3];
  const float* as1 = (const float*)d_in[4];
  const float* an1 = (const float*)d_in[5];
  const float* b1  = (const float*)d_in[6];
  const float* W2  = (const float*)d_in[7];
  const float* as2 = (const float*)d_in[8];
  const float* an2 = (const float*)d_in[9];
  const float* b2  = (const float*)d_in[10];
  const float* fc1 = (const float*)d_in[11];
  const float* fc2 = (const float*)d_in[12];
  float* out = (float*)d_out;

  // workspace layout: amask [B][110][2] u64, then h1 [B][110][120] f32
  unsigned long long* amask = (unsigned long long*)d_ws;
  const size_t amask_bytes = (size_t)NB * NV * 2 * sizeof(unsigned long long);
  float* h1 = (float*)((char*)d_ws + amask_bytes);

  gat1_kernel<<<NB, T1, 0, stream>>>(X, A, M, W1, as1, an1, b1, h1, amask);
  gat2_kernel<<<NB, T2, 0, stream>>>(h1, amask, W2, as2, an2, b2, fc1, fc2, out);
}

// Round 3
// 782.646 us; speedup vs baseline: 1.2452x; 1.2452x over previous
//
#include <hip/hip_runtime.h>
#include <math.h>

#define NB 2048
#define NV 110
#define NH1 5
#define NF1 24
#define NH2 3
#define NF2 3
#define C1 (NH1*NF1)   // 120
#define NEGV -9e15f
#define LALPHA 0.2f

constexpr int NN = NV*NV;          // 12100
constexpr int T1 = 512;
constexpr int T2 = 512;
constexpr int KP = 136;            // padded K stride (halves): 272B = 68 dwords = 4 mod 32 -> 2-way free

typedef _Float16 f16;
typedef f16  f16x8 __attribute__((ext_vector_type(8)));
typedef f16  f16x4 __attribute__((ext_vector_type(4)));
typedef float f32x4 __attribute__((ext_vector_type(4)));

__device__ __forceinline__ f32x4 mfma16(f16x8 a, f16x8 b, f32x4 c) {
  return __builtin_amdgcn_mfma_f32_16x16x32_f16(a, b, c, 0, 0, 0);
}

__device__ __forceinline__ float lrelu(float x){ return x > 0.f ? x : LALPHA*x; }
__device__ __forceinline__ float sigm(float x){ return 1.f/(1.f+__expf(-x)); }
__device__ __forceinline__ float wmax(float v){
  #pragma unroll
  for (int d=32; d; d>>=1) v = fmaxf(v, __shfl_xor(v,d));
  return v;
}
__device__ __forceinline__ float wsum(float v){
  #pragma unroll
  for (int d=32; d; d>>=1) v += __shfl_xor(v,d);
  return v;
}

// ---------------- Kernel 1: mask-gate + GAT layer 1 (concat), MFMA ----------------
__global__ __launch_bounds__(T1) void gat1_kernel(
  const float* __restrict__ X, const float* __restrict__ A,
  const float* __restrict__ M, const float* __restrict__ W1,
  const float* __restrict__ as1, const float* __restrict__ an1,
  const float* __restrict__ b1,
  f16* __restrict__ h1, unsigned long long* __restrict__ amask)
{
  // LDS: 30464 + 34816 + 34816 + 2200 + 2200 + 1760 = 106,256 B
  __shared__ __attribute__((aligned(16))) f16 sXm [112*KP];  // Xm rows (M=112 pad), later attn buf 0
  __shared__ __attribute__((aligned(16))) f16 sW1t[128*KP];  // W1^T rows (N=128 pad), later attn buf 1
  __shared__ __attribute__((aligned(16))) f16 sFt [128*KP];  // feats^T: sFt[f][m]
  __shared__ float sES[NH1*NV];
  __shared__ float sEN[NH1*NV];
  __shared__ unsigned long long sAM[NV*2];

  const int b = blockIdx.x, tid = threadIdx.x;
  const int wave = tid >> 6, lane = tid & 63;
  const int lr = lane & 15, lh = lane >> 4;       // MFMA row-in-tile, k-block
  const float* __restrict__ Xb = X + (size_t)b*NN;
  const float* __restrict__ Ab = A + (size_t)b*NN;

  // --- zero-init LDS (pads must be exactly 0 for MFMA tails) ---
  for (int i = tid; i < 112*KP/8; i += T1) ((uint4*)sXm )[i] = uint4{0,0,0,0};
  for (int i = tid; i < 128*KP/8; i += T1) ((uint4*)sW1t)[i] = uint4{0,0,0,0};
  for (int i = tid; i < 128*KP/8; i += T1) ((uint4*)sFt )[i] = uint4{0,0,0,0};
  __syncthreads();

  // --- stage Xm = X*sigmoid(M) (f16), W1^T (f16), adjacency bitmask ---
  for (int i = tid; i < NN; i += T1) {
    const int n = i/NV, k = i%NV;
    sXm[n*KP + k] = (f16)(Xb[i] * sigm(M[i]));
  }
  for (int t = tid; t < NH1*NF1*NV; t += T1) {   // i fastest: contiguous LDS writes
    const int h = t/(NF1*NV), r = t%(NF1*NV), f = r/NV, i = r%NV;
    sW1t[(h*NF1 + f)*KP + i] = (f16)W1[((size_t)h*NV + i)*NF1 + f];
  }
  for (int n = wave; n < NV; n += T1/64) {
    unsigned long long m0 = __ballot(Ab[n*NV + lane] > 0.f);
    const int mm = 64 + lane;
    unsigned long long m1 = __ballot((mm < NV) && (Ab[n*NV + mm] > 0.f));
    if (lane == 0) {
      sAM[2*n] = m0; sAM[2*n+1] = m1;
      amask[(size_t)b*2*NV + 2*n]     = m0;
      amask[(size_t)b*2*NV + 2*n + 1] = m1;
    }
  }
  __syncthreads();

  // --- GEMM1: feats = Xm(110x110) @ W1cat(110x120), wave w owns N-tile w ---
  {
    f16x8 bfrag[4];
    #pragma unroll
    for (int k = 0; k < 4; ++k)
      bfrag[k] = *(const f16x8*)&sW1t[(wave*16 + lr)*KP + k*32 + lh*8];
    #pragma unroll
    for (int m = 0; m < 7; ++m) {
      f32x4 acc = {0.f,0.f,0.f,0.f};
      #pragma unroll
      for (int k = 0; k < 4; ++k) {
        f16x8 af = *(const f16x8*)&sXm[(m*16 + lr)*KP + k*32 + lh*8];
        acc = mfma16(af, bfrag[k], acc);
      }
      // transpose-store: sFt[n][m'] ; n = wave*16+lr, m' = m*16+lh*4+r
      f16x4 v;
      #pragma unroll
      for (int r = 0; r < 4; ++r) v[r] = (f16)acc[r];
      *(f16x4*)&sFt[(wave*16 + lr)*KP + m*16 + lh*4] = v;
    }
  }
  __syncthreads();

  // --- attention logits per (head, node) from sFt ---
  for (int t = tid; t < NH1*NV; t += T1) {
    const int h = t/NV, n = t%NV;
    float es = 0.f, en = 0.f;
    #pragma unroll
    for (int f = 0; f < NF1; ++f) {
      const float v = (float)sFt[(h*NF1 + f)*KP + n];
      es += v*as1[h*NF1+f];
      en += v*an1[h*NF1+f];
    }
    sES[t] = es; sEN[t] = en;
  }
  __syncthreads();

  // --- per-head: masked softmax (f16 attn into dead Xm/W1t buffers) + MFMA aggregate ---
  for (int pass = 0; pass < 3; ++pass) {
    const int hA = 2*pass;
    const int nh = (hA+1 < NH1) ? 2 : 1;
    for (int rr = wave; rr < nh*NV; rr += T1/64) {
      const int hh = rr/NV, n = rr%NV, h = hA + hh;
      f16* ab = hh ? sW1t : sXm;
      const float esv = sES[h*NV + n];
      const unsigned long long am0 = sAM[2*n], am1 = sAM[2*n+1];
      float v0 = lrelu(esv + sEN[h*NV + lane]);
      if (!((am0 >> lane) & 1ull)) v0 = NEGV;
      const int mm = 64 + lane;
      float v1 = NEGV;
      if (mm < NV) {
        v1 = lrelu(esv + sEN[h*NV + mm]);
        if (!((am1 >> lane) & 1ull)) v1 = NEGV;
      }
      const float mx = wmax(fmaxf(v0, v1));
      const float p0 = __expf(v0 - mx);
      const float p1 = (mm < NV) ? __expf(v1 - mx) : 0.f;
      const float inv = 1.f / wsum(p0 + p1);
      ab[n*KP + lane] = (f16)(p0 * inv);
      if (mm < NV) ab[n*KP + mm] = (f16)(p1 * inv);
    }
    __syncthreads();
    // GEMM2: h_h = attn_h(110x110) @ feats_h(110x24)
    const int hh = wave & 1, nt = (wave >> 1) & 1, mh = wave >> 2;
    if (hh < nh) {
      const int h = hA + hh;
      const f16* ab = hh ? sW1t : sXm;
      f16x8 bf[4];
      #pragma unroll
      for (int k = 0; k < 4; ++k)
        bf[k] = *(const f16x8*)&sFt[(h*NF1 + nt*16 + lr)*KP + k*32 + lh*8];
      const int mlo = mh ? 4 : 0, mhi = mh ? 7 : 4;
      const int f = nt*16 + lr;
      for (int m = mlo; m < mhi; ++m) {
        f32x4 acc = {0.f,0.f,0.f,0.f};
        #pragma unroll
        for (int k = 0; k < 4; ++k) {
          f16x8 af = *(const f16x8*)&ab[(m*16 + lr)*KP + k*32 + lh*8];
          acc = mfma16(af, bf[k], acc);
        }
        if (f < NF1) {
          const float bv = b1[f];
          #pragma unroll
          for (int r = 0; r < 4; ++r) {
            const int mg = m*16 + lh*4 + r;
            if (mg < NV)
              h1[((size_t)b*NV + mg)*C1 + h*NF1 + f] = (f16)lrelu(acc[r] + bv);
          }
        }
      }
    }
    __syncthreads();
  }
}

// ------------- Kernel 2: GAT layer 2 (average) + heads + readout -------------
__global__ __launch_bounds__(T2) void gat2_kernel(
  const f16* __restrict__ h1, const unsigned long long* __restrict__ amask,
  const float* __restrict__ W2, const float* __restrict__ as2,
  const float* __restrict__ an2, const float* __restrict__ b2,
  const float* __restrict__ fc1w, const float* __restrict__ fc2w,
  float* __restrict__ out)
{
  __shared__ float sH[NV*C1];        // h1 staged, later attn buf
  __shared__ float sW2[NH2*NF2*C1];  // W2 transposed [g][f2][c]
  __shared__ float sF2[NH2*NF2*NV];  // feats2 [g][f2][n]
  __shared__ float sES[NH2*NV], sEN[NH2*NV];
  __shared__ float sHS[NV*NF2];      // head-sum accumulator
  __shared__ float sT[NV];
  __shared__ float sS[NV];
  __shared__ unsigned long long sAM[NV*2];

  const int b = blockIdx.x, tid = threadIdx.x;
  const int wave = tid >> 6, lane = tid & 63;

  for (int i = tid; i < NV*C1; i += T2) sH[i] = (float)h1[(size_t)b*NV*C1 + i];
  for (int i = tid; i < NH2*C1*NF2; i += T2) {
    const int g = i/(C1*NF2), r = i%(C1*NF2), c = r/NF2, f2 = r%NF2;
    sW2[(g*NF2 + f2)*C1 + c] = W2[i];
  }
  for (int i = tid; i < 2*NV; i += T2) sAM[i] = amask[(size_t)b*2*NV + i];
  for (int i = tid; i < NV*NF2; i += T2) sHS[i] = 0.f;
  __syncthreads();

  // feats2[g][f2][n] = sum_c h1[n][c] * W2[g][c][f2]
  for (int t = tid; t < NV*NH2*NF2; t += T2) {
    const int n = t/(NH2*NF2), r = t%(NH2*NF2), g = r/NF2, f2 = r%NF2;
    const float* hr = &sH[n*C1];
    const float* wr = &sW2[(g*NF2 + f2)*C1];
    float acc = 0.f;
    for (int c = 0; c < C1; c += 4) {
      const float4 hv = *(const float4*)(hr + c);
      const float4 wv = *(const float4*)(wr + c);
      acc += hv.x*wv.x + hv.y*wv.y + hv.z*wv.z + hv.w*wv.w;
    }
    sF2[(g*NF2 + f2)*NV + n] = acc;
  }
  __syncthreads();

  for (int t = tid; t < NH2*NV; t += T2) {
    const int g = t/NV, n = t%NV;
    float es = 0.f, en = 0.f;
    #pragma unroll
    for (int f2 = 0; f2 < NF2; ++f2) {
      const float v = sF2[(g*NF2 + f2)*NV + n];
      es += v*as2[g*NF2+f2];
      en += v*an2[g*NF2+f2];
    }
    sES[t] = es; sEN[t] = en;
  }
  __syncthreads();

  float* attn = sH;   // h1 staging dead after feats2
  for (int g = 0; g < NH2; ++g) {
    for (int n = wave; n < NV; n += T2/64) {
      const float esv = sES[g*NV+n];
      const unsigned long long am0 = sAM[2*n], am1 = sAM[2*n+1];
      float v0 = lrelu(esv + sEN[g*NV + lane]);
      if (!((am0>>lane)&1ull)) v0 = NEGV;
      const int mm = 64+lane;
      float v1 = NEGV;
      if (mm < NV) {
        v1 = lrelu(esv + sEN[g*NV+mm]);
        if (!((am1>>lane)&1ull)) v1 = NEGV;
      }
      const float mx = wmax(fmaxf(v0,v1));
      const float p0 = __expf(v0-mx);
      const float p1 = (mm<NV)? __expf(v1-mx) : 0.f;
      const float inv = 1.f/wsum(p0+p1);
      attn[n*NV+lane] = p0*inv;
      if (mm<NV) attn[n*NV+mm] = p1*inv;
    }
    __syncthreads();
    if (tid < NV*NF2) {
      const int n = tid/NF2, f2 = tid%NF2;
      const float* ar = &attn[n*NV];
      const float* fr = &sF2[(g*NF2+f2)*NV];
      float acc = 0.f;
      for (int m = 0; m < NV; ++m) acc += ar[m]*fr[m];
      sHS[tid] += acc;
    }
    __syncthreads();
  }

  // t[n] = sigmoid( lrelu(mean_g + b2) . fc1 )
  if (tid < NV) {
    float dot = 0.f;
    #pragma unroll
    for (int f2 = 0; f2 < NF2; ++f2) {
      const float h2v = lrelu(sHS[tid*NF2+f2]*(1.f/NH2) + b2[f2]);
      dot += h2v*fc1w[f2];
    }
    sT[tid] = sigm(dot);
  }
  __syncthreads();
  if (tid < NV) {
    float acc = 0.f;
    for (int i = 0; i < NV; ++i) acc += sT[i]*fc2w[i*NV + tid];
    sS[tid] = acc;
  }
  __syncthreads();
  if (wave == 0) {
    const float s0 = sS[lane];
    const float s1 = (64+lane < NV) ? sS[64+lane] : -1e38f;
    const float mx = wmax(fmaxf(s0,s1));
    const float p0 = __expf(s0-mx);
    const float p1 = (64+lane < NV) ? __expf(s1-mx) : 0.f;
    const float sum = wsum(p0+p1);
    float val = sT[lane]*p0 + ((64+lane<NV)? sT[64+lane]*p1 : 0.f);
    val = wsum(val);
    if (lane == 0) out[b] = val/sum;
  }
}

extern "C" void kernel_launch(void* const* d_in, const int* in_sizes, int n_in,
                              void* d_out, int out_size, void* d_ws, size_t ws_size,
                              hipStream_t stream) {
  const float* X   = (const float*)d_in[0];
  const float* A   = (const float*)d_in[1];
  const float* M   = (const float*)d_in[2];
  const float* W1  = (const float*)d_in[3];
  const float* as1 = (const float*)d_in[4];
  const float* an1 = (const float*)d_in[5];
  const float* b1  = (const float*)d_in[6];
  const float* W2  = (const float*)d_in[7];
  const float* as2 = (const float*)d_in[8];
  const float* an2 = (const float*)d_in[9];
  const float* b2  = (const float*)d_in[10];
  const float* fc1 = (const float*)d_in[11];
  const float* fc2 = (const float*)d_in[12];
  float* out = (float*)d_out;

  // workspace: amask [B][110][2] u64, then h1 [B][110][120] f16
  unsigned long long* amask = (unsigned long long*)d_ws;
  const size_t amask_bytes = (size_t)NB * NV * 2 * sizeof(unsigned long long);
  f16* h1 = (f16*)((char*)d_ws + amask_bytes);

  gat1_kernel<<<NB, T1, 0, stream>>>(X, A, M, W1, as1, an1, b1, h1, amask);
  gat2_kernel<<<NB, T2, 0, stream>>>(h1, amask, W2, as2, an2, b2, fc1, fc2, out);
}

// Round 4
// 424.794 us; speedup vs baseline: 2.2943x; 1.8424x over previous
//
#include <hip/hip_runtime.h>
#include <math.h>

#define NB 2048
#define NV 110
#define NH1 5
#define NF1 24
#define NH2 3
#define NF2 3
#define C1 (NH1*NF1)   // 120
#define NEGV -9e15f
#define LALPHA 0.2f

constexpr int NN = NV*NV;          // 12100
constexpr int T1 = 512;
constexpr int KP = 136;            // padded K stride (halves): 272B -> 2-way bank alias (free)

typedef _Float16 f16;
typedef f16  f16x8 __attribute__((ext_vector_type(8)));
typedef f16  f16x4 __attribute__((ext_vector_type(4)));
typedef float f32x4 __attribute__((ext_vector_type(4)));

__device__ __forceinline__ f32x4 mfma16(f16x8 a, f16x8 b, f32x4 c) {
  return __builtin_amdgcn_mfma_f32_16x16x32_f16(a, b, c, 0, 0, 0);
}
__device__ __forceinline__ float lrelu(float x){ return x > 0.f ? x : LALPHA*x; }
__device__ __forceinline__ float sigm(float x){ return 1.f/(1.f+__expf(-x)); }
__device__ __forceinline__ float wmax(float v){
  #pragma unroll
  for (int d=32; d; d>>=1) v = fmaxf(v, __shfl_xor(v,d));
  return v;
}
__device__ __forceinline__ float wsum(float v){
  #pragma unroll
  for (int d=32; d; d>>=1) v += __shfl_xor(v,d);
  return v;
}
__device__ __forceinline__ f32x4 ld4u(const float* p){
  f32x4 v; __builtin_memcpy(&v, p, 16); return v;   // 4B-aligned vector load
}

// ---- Kernel 0: precompute sigmoid(M), W1^T f16 (zero-padded), W2^T f16 ----
__global__ void precomp_kernel(const float* __restrict__ M, const float* __restrict__ W1,
                               const float* __restrict__ W2,
                               float* __restrict__ Msig, f16* __restrict__ W1tg,
                               f16* __restrict__ W2tg) {
  const int i = blockIdx.x*256 + threadIdx.x;
  if (i < NN) {
    Msig[i] = sigm(M[i]);
  } else if (i < NN + 128*KP) {
    const int j = i - NN, f = j/KP, k = j%KP;
    f16 v = (f16)0.f;
    if (f < C1 && k < NV) v = (f16)W1[(f/NF1)*(NV*NF1) + k*NF1 + (f%NF1)];
    W1tg[f*KP + k] = v;
  } else if (i < NN + 128*KP + 16*KP) {
    const int j = i - NN - 128*KP, r = j/KP, k = j%KP;
    f16 v = (f16)0.f;
    if (r < NH2*NF2 && k < C1) v = (f16)W2[(r/NF2)*(C1*NF2) + k*NF2 + (r%NF2)];
    W2tg[r*KP + k] = v;
  }
}

// ---- Kernel 1: fully fused GAT (layer1 + layer2 + readout), one block/batch ----
__global__ __launch_bounds__(T1, 4) void gat_fused(
  const float* __restrict__ X, const float* __restrict__ A,
  const float* __restrict__ Msig, const f16* __restrict__ W1tg,
  const float* __restrict__ as1, const float* __restrict__ an1,
  const float* __restrict__ b1,  const f16* __restrict__ W2tg,
  const float* __restrict__ as2, const float* __restrict__ an2,
  const float* __restrict__ b2,  const float* __restrict__ fc1w,
  const float* __restrict__ fc2w, float* __restrict__ out)
{
  // LDS total = 30464+34816+4352+2200+2200+1760+448+448 = 76,688 B  (2 blocks/CU)
  __shared__ __attribute__((aligned(16))) f16 sXm [112*KP]; // Xm / attn1 / h1[n][c]
  __shared__ __attribute__((aligned(16))) f16 sFt [128*KP]; // feats^T / attn2
  __shared__ __attribute__((aligned(16))) f16 sF2t[16*KP];  // feats2^T
  __shared__ float sES[NH1*NV];
  __shared__ float sEN[NH1*NV];
  __shared__ unsigned long long sAM[2*NV];
  __shared__ float sT[112];
  __shared__ float sS[112];

  const int b = blockIdx.x, tid = threadIdx.x;
  const int wave = tid >> 6, lane = tid & 63;
  const int lr = lane & 15, lh = lane >> 4;
  const float* __restrict__ Xb = X + (size_t)b*NN;
  const float* __restrict__ Ab = A + (size_t)b*NN;

  // --- zero-init (pads must be 0 for MFMA tails) ---
  for (int i = tid; i < (112*KP)/8; i += T1) ((uint4*)sXm )[i] = uint4{0,0,0,0};
  for (int i = tid; i < (128*KP)/8; i += T1) ((uint4*)sFt )[i] = uint4{0,0,0,0};
  for (int i = tid; i < (16*KP)/8;  i += T1) ((uint4*)sF2t)[i] = uint4{0,0,0,0};
  __syncthreads();

  // --- stage Xm = X * Msig (float4 loads), adjacency ballot ---
  for (int t = tid; t < NV*28; t += T1) {
    const int n = t/28, c = t%28, k = 4*c;
    if (c < 27) {
      f32x4 x = ld4u(Xb + n*NV + k);
      f32x4 m = ld4u(Msig + n*NV + k);
      f16x4 v;
      #pragma unroll
      for (int j = 0; j < 4; ++j) v[j] = (f16)(x[j]*m[j]);
      *(f16x4*)&sXm[n*KP + k] = v;
    } else {
      sXm[n*KP + 108] = (f16)(Xb[n*NV+108]*Msig[n*NV+108]);
      sXm[n*KP + 109] = (f16)(Xb[n*NV+109]*Msig[n*NV+109]);
    }
  }
  for (int n = wave; n < NV; n += 8) {
    unsigned long long m0 = __ballot(Ab[n*NV + lane] > 0.f);
    const int mm = 64 + lane;
    unsigned long long m1 = __ballot((mm < NV) && (Ab[n*NV + mm] > 0.f));
    if (lane == 0) { sAM[2*n] = m0; sAM[2*n+1] = m1; }
  }
  // W1 B-fragment straight from global (L2-resident, zero-padded)
  f16x8 bW[4];
  #pragma unroll
  for (int k = 0; k < 4; ++k)
    bW[k] = *(const f16x8*)&W1tg[(wave*16 + lr)*KP + k*32 + lh*8];
  __syncthreads();

  // --- GEMM1: feats = Xm(110x110) @ W1cat(110x120); wave w -> f-tile w ---
  #pragma unroll
  for (int m = 0; m < 7; ++m) {
    f32x4 acc = {0.f,0.f,0.f,0.f};
    #pragma unroll
    for (int k = 0; k < 4; ++k) {
      f16x8 af = *(const f16x8*)&sXm[(m*16 + lr)*KP + k*32 + lh*8];
      acc = mfma16(af, bW[k], acc);
    }
    f16x4 v;
    #pragma unroll
    for (int r = 0; r < 4; ++r) v[r] = (f16)acc[r];
    *(f16x4*)&sFt[(wave*16 + lr)*KP + m*16 + lh*4] = v;   // sFt[f][m]
  }
  __syncthreads();

  // --- layer1 logits ---
  for (int t = tid; t < NH1*NV; t += T1) {
    const int h = t/NV, n = t%NV;
    float es = 0.f, en = 0.f;
    #pragma unroll
    for (int f = 0; f < NF1; ++f) {
      const float v = (float)sFt[(h*NF1 + f)*KP + n];
      es += v*as1[h*NF1+f];
      en += v*an1[h*NF1+f];
    }
    sES[t] = es; sEN[t] = en;
  }
  __syncthreads();

  // --- 5 head passes: softmax -> sXm, GEMM2, h1 kept in f16 regs ---
  const int nt = wave & 1, mh = wave >> 1;
  f16 h1r[5][2][4];
  #pragma unroll
  for (int p = 0; p < 5; ++p) {
    for (int n = wave; n < NV; n += 8) {
      const float esv = sES[p*NV + n];
      const unsigned long long am0 = sAM[2*n], am1 = sAM[2*n+1];
      float v0 = lrelu(esv + sEN[p*NV + lane]);
      if (!((am0 >> lane) & 1ull)) v0 = NEGV;
      const int mm = 64 + lane;
      float v1 = NEGV;
      if (mm < NV) {
        v1 = lrelu(esv + sEN[p*NV + mm]);
        if (!((am1 >> lane) & 1ull)) v1 = NEGV;
      }
      const float mx = wmax(fmaxf(v0, v1));
      const float e0 = __expf(v0 - mx);
      const float e1 = (mm < NV) ? __expf(v1 - mx) : 0.f;
      const float inv = 1.f / wsum(e0 + e1);
      sXm[n*KP + lane] = (f16)(e0 * inv);
      if (mm < NV) sXm[n*KP + mm] = (f16)(e1 * inv);
    }
    __syncthreads();
    // GEMM2: h_p = attn_p(110x110) @ feats_p(110x24)
    f16x8 bf[4];
    #pragma unroll
    for (int k = 0; k < 4; ++k)
      bf[k] = *(const f16x8*)&sFt[(p*NF1 + nt*16 + lr)*KP + k*32 + lh*8];
    const int fl = nt*16 + lr;
    const float bv = (fl < NF1) ? b1[fl] : 0.f;
    #pragma unroll
    for (int mi = 0; mi < 2; ++mi) {
      const int m = 2*mh + mi;
      if (m < 7) {
        f32x4 acc = {0.f,0.f,0.f,0.f};
        #pragma unroll
        for (int k = 0; k < 4; ++k) {
          f16x8 af = *(const f16x8*)&sXm[(m*16 + lr)*KP + k*32 + lh*8];
          acc = mfma16(af, bf[k], acc);
        }
        #pragma unroll
        for (int r = 0; r < 4; ++r) h1r[p][mi][r] = (f16)lrelu(acc[r] + bv);
      }
    }
    __syncthreads();
  }

  // --- dump h1 regs -> sXm[n][c] (row-major, zero-padded cols 120..135) ---
  {
    const int fl = nt*16 + lr;
    #pragma unroll
    for (int p = 0; p < 5; ++p) {
      #pragma unroll
      for (int mi = 0; mi < 2; ++mi) {
        const int m = 2*mh + mi;
        if (m < 7 && fl < NF1) {
          #pragma unroll
          for (int r = 0; r < 4; ++r) {
            const int mg = m*16 + lh*4 + r;
            if (mg < NV) sXm[mg*KP + p*NF1 + fl] = h1r[p][mi][r];
          }
        }
      }
    }
  }
  __syncthreads();

  // --- feats2 = h1(110x120) @ W2cat(120x9); wave w<7 -> m-tile w ---
  {
    f16x8 bW2[4];
    #pragma unroll
    for (int k = 0; k < 4; ++k)
      bW2[k] = *(const f16x8*)&W2tg[lr*KP + k*32 + lh*8];
    if (wave < 7) {
      f32x4 acc = {0.f,0.f,0.f,0.f};
      #pragma unroll
      for (int k = 0; k < 4; ++k) {
        f16x8 af = *(const f16x8*)&sXm[(wave*16 + lr)*KP + k*32 + lh*8];
        acc = mfma16(af, bW2[k], acc);
      }
      if (lr < NH2*NF2) {
        #pragma unroll
        for (int r = 0; r < 4; ++r) {
          const int mg = wave*16 + lh*4 + r;
          if (mg < NV) sF2t[lr*KP + mg] = (f16)acc[r];   // sF2t[g*3+f2][n]
        }
      }
    }
  }
  __syncthreads();

  // --- layer2 logits ---
  for (int t = tid; t < NH2*NV; t += T1) {
    const int g = t/NV, n = t%NV;
    float es = 0.f, en = 0.f;
    #pragma unroll
    for (int f = 0; f < NF2; ++f) {
      const float v = (float)sF2t[(g*NF2 + f)*KP + n];
      es += v*as2[g*NF2+f];
      en += v*an2[g*NF2+f];
    }
    sES[t] = es; sEN[t] = en;
  }
  __syncthreads();

  // --- 3 head passes layer2: softmax -> sFt, GEMM3 accumulates over heads ---
  f32x4 acc2 = {0.f,0.f,0.f,0.f};
  for (int g = 0; g < NH2; ++g) {
    for (int n = wave; n < NV; n += 8) {
      const float esv = sES[g*NV + n];
      const unsigned long long am0 = sAM[2*n], am1 = sAM[2*n+1];
      float v0 = lrelu(esv + sEN[g*NV + lane]);
      if (!((am0 >> lane) & 1ull)) v0 = NEGV;
      const int mm = 64 + lane;
      float v1 = NEGV;
      if (mm < NV) {
        v1 = lrelu(esv + sEN[g*NV + mm]);
        if (!((am1 >> lane) & 1ull)) v1 = NEGV;
      }
      const float mx = wmax(fmaxf(v0, v1));
      const float e0 = __expf(v0 - mx);
      const float e1 = (mm < NV) ? __expf(v1 - mx) : 0.f;
      const float inv = 1.f / wsum(e0 + e1);
      sFt[n*KP + lane] = (f16)(e0 * inv);
      if (mm < NV) sFt[n*KP + mm] = (f16)(e1 * inv);
    }
    __syncthreads();
    if (wave < 7) {
      const int brow = (lr < NF2) ? (g*NF2 + lr) : 9;   // rows 9..15 are zero
      f16x8 bf[4];
      #pragma unroll
      for (int k = 0; k < 4; ++k)
        bf[k] = *(const f16x8*)&sF2t[brow*KP + k*32 + lh*8];
      #pragma unroll
      for (int k = 0; k < 4; ++k) {
        f16x8 af = *(const f16x8*)&sFt[(wave*16 + lr)*KP + k*32 + lh*8];
        acc2 = mfma16(af, bf[k], acc2);   // sums over heads via C-accumulate
      }
    }
    __syncthreads();
  }

  // --- t[n] = sigmoid( lrelu(mean_g + b2) . fc1 ) ---
  if (wave < 7) {
    const float fcv = (lr < NF2) ? fc1w[lr] : 0.f;
    const float b2v = (lr < NF2) ? b2[lr]  : 0.f;
    #pragma unroll
    for (int r = 0; r < 4; ++r) {
      float hv = (lr < NF2) ? lrelu(acc2[r]*(1.f/NH2) + b2v)*fcv : 0.f;
      hv += __shfl_xor(hv, 1);
      hv += __shfl_xor(hv, 2);
      hv += __shfl_xor(hv, 4);
      hv += __shfl_xor(hv, 8);
      if (lr == 0) {
        const int mg = wave*16 + lh*4 + r;
        if (mg < NV) sT[mg] = sigm(hv);
      }
    }
  }
  __syncthreads();
  // --- s = t @ fc2 ---
  if (tid < NV) {
    float acc = 0.f;
    for (int n = 0; n < NV; ++n) acc += sT[n]*fc2w[n*NV + tid];
    sS[tid] = acc;
  }
  __syncthreads();
  // --- out[b] = sum_m t[m]*softmax(s)[m] ---
  if (wave == 0) {
    const float s0 = sS[lane];
    const float s1 = (64+lane < NV) ? sS[64+lane] : -1e38f;
    const float mx = wmax(fmaxf(s0, s1));
    const float p0 = __expf(s0 - mx);
    const float p1 = (64+lane < NV) ? __expf(s1 - mx) : 0.f;
    const float sum = wsum(p0 + p1);
    float val = sT[lane]*p0 + ((64+lane < NV) ? sT[64+lane]*p1 : 0.f);
    val = wsum(val);
    if (lane == 0) out[b] = val/sum;
  }
}

extern "C" void kernel_launch(void* const* d_in, const int* in_sizes, int n_in,
                              void* d_out, int out_size, void* d_ws, size_t ws_size,
                              hipStream_t stream) {
  const float* X   = (const float*)d_in[0];
  const float* A   = (const float*)d_in[1];
  const float* M   = (const float*)d_in[2];
  const float* W1  = (const float*)d_in[3];
  const float* as1 = (const float*)d_in[4];
  const float* an1 = (const float*)d_in[5];
  const float* b1  = (const float*)d_in[6];
  const float* W2  = (const float*)d_in[7];
  const float* as2 = (const float*)d_in[8];
  const float* an2 = (const float*)d_in[9];
  const float* b2  = (const float*)d_in[10];
  const float* fc1 = (const float*)d_in[11];
  const float* fc2 = (const float*)d_in[12];
  float* out = (float*)d_out;

  // ws layout: Msig f32[12100] | W1tg f16[128*136] | W2tg f16[16*136]
  float* Msig = (float*)d_ws;                                   // 48,400 B
  f16* W1tg = (f16*)((char*)d_ws + 48400);                      // 34,816 B (16B-aligned)
  f16* W2tg = (f16*)((char*)d_ws + 48400 + 34816);              // 4,352 B

  const int pre_items = NN + 128*KP + 16*KP;
  precomp_kernel<<<(pre_items + 255)/256, 256, 0, stream>>>(M, W1, W2, Msig, W1tg, W2tg);
  gat_fused<<<NB, T1, 0, stream>>>(X, A, Msig, W1tg, as1, an1, b1, W2tg,
                                   as2, an2, b2, fc1, fc2, out);
}

// Round 5
// 193.474 us; speedup vs baseline: 5.0373x; 2.1956x over previous
//
#include <hip/hip_runtime.h>
#include <math.h>

#define NB 2048
#define NV 110
#define NH1 5
#define NF1 24
#define NH2 3
#define NF2 3
#define C1 (NH1*NF1)   // 120
#define LALPHA 0.2f

constexpr int NN = NV*NV;          // 12100
constexpr int T1 = 512;
constexpr int KP = 136;            // padded K stride (halves)
constexpr int W1ROWS = 144;        // 120 feats cols + pad + 10 logit cols + pad

typedef _Float16 f16;
typedef f16  f16x8 __attribute__((ext_vector_type(8)));
typedef f16  f16x4 __attribute__((ext_vector_type(4)));
typedef float f32x4 __attribute__((ext_vector_type(4)));

__device__ __forceinline__ f32x4 mfma16(f16x8 a, f16x8 b, f32x4 c) {
  return __builtin_amdgcn_mfma_f32_16x16x32_f16(a, b, c, 0, 0, 0);
}
__device__ __forceinline__ float lrelu(float x){ return x > 0.f ? x : LALPHA*x; }
__device__ __forceinline__ float sigm(float x){ return 1.f/(1.f+__expf(-x)); }
__device__ __forceinline__ float wmax(float v){
  #pragma unroll
  for (int d=32; d; d>>=1) v = fmaxf(v, __shfl_xor(v,d));
  return v;
}
__device__ __forceinline__ float wsum(float v){
  #pragma unroll
  for (int d=32; d; d>>=1) v += __shfl_xor(v,d);
  return v;
}
__device__ __forceinline__ f32x4 ld4u(const float* p){
  f32x4 v; __builtin_memcpy(&v, p, 16); return v;
}

// ---- Kernel 0: precompute sigmoid(M), augmented W1^T, augmented W2^T ----
// W1tg rows: 0..119 = W1^T cat; 128+h = es-col head h; 133+h = en-col; rest 0
// W2tg rows: 0..8 = W2^T cat; 9+g = es2-col; 12+g = en2-col; 15 = 0
__global__ void precomp_kernel(const float* __restrict__ M, const float* __restrict__ W1,
                               const float* __restrict__ as1, const float* __restrict__ an1,
                               const float* __restrict__ W2, const float* __restrict__ as2,
                               const float* __restrict__ an2,
                               float* __restrict__ Msig, f16* __restrict__ W1tg,
                               f16* __restrict__ W2tg) {
  const int i = blockIdx.x*256 + threadIdx.x;
  if (i < NN) {
    Msig[i] = sigm(M[i]);
  } else if (i < NN + W1ROWS*KP) {
    const int j = i - NN, f = j/KP, k = j%KP;
    float v = 0.f;
    if (k < NV) {
      if (f < C1) {
        v = W1[(f/NF1)*(NV*NF1) + k*NF1 + (f%NF1)];
      } else if (f >= 128 && f < 133) {
        const int h = f - 128;
        for (int ff = 0; ff < NF1; ++ff)
          v += W1[h*(NV*NF1) + k*NF1 + ff] * as1[h*NF1 + ff];
      } else if (f >= 133 && f < 138) {
        const int h = f - 133;
        for (int ff = 0; ff < NF1; ++ff)
          v += W1[h*(NV*NF1) + k*NF1 + ff] * an1[h*NF1 + ff];
      }
    }
    W1tg[f*KP + k] = (f16)v;
  } else if (i < NN + W1ROWS*KP + 16*KP) {
    const int j = i - NN - W1ROWS*KP, r = j/KP, k = j%KP;
    float v = 0.f;
    if (k < C1) {
      if (r < 9) {
        v = W2[(r/NF2)*(C1*NF2) + k*NF2 + (r%NF2)];
      } else if (r < 12) {
        const int g = r - 9;
        for (int f2 = 0; f2 < NF2; ++f2)
          v += W2[g*(C1*NF2) + k*NF2 + f2] * as2[g*NF2 + f2];
      } else if (r < 15) {
        const int g = r - 12;
        for (int f2 = 0; f2 < NF2; ++f2)
          v += W2[g*(C1*NF2) + k*NF2 + f2] * an2[g*NF2 + f2];
      }
    }
    W2tg[r*KP + k] = (f16)v;
  }
}

// ---- fully fused GAT: layer1 + layer2 + readout, one block per batch ----
__global__ __launch_bounds__(T1, 4) void gat_fused(
  const float* __restrict__ X, const float* __restrict__ A,
  const float* __restrict__ Msig, const f16* __restrict__ W1tg,
  const float* __restrict__ b1,  const f16* __restrict__ W2tg,
  const float* __restrict__ b2,  const float* __restrict__ fc1w,
  const float* __restrict__ fc2w, float* __restrict__ out)
{
  // LDS = 30464+34816+4352+2240+2240+1760+5376 = 81,248 B  (2 blocks/CU)
  __shared__ __attribute__((aligned(16))) f16 sXm [112*KP]; // Xm / attn1 / h1
  __shared__ __attribute__((aligned(16))) f16 sFt [128*KP]; // feats^T / attn2
  __shared__ __attribute__((aligned(16))) f16 sF2t[16*KP];  // feats2^T
  __shared__ float sES[NH1*112];
  __shared__ float sEN[NH1*112];
  __shared__ unsigned long long sAM[2*NV];
  __shared__ float sCMB[3][112][4];     // partial expsums [head][row][quarter]

  const int b = blockIdx.x, tid = threadIdx.x;
  const int wave = tid >> 6, lane = tid & 63;
  const int lr = lane & 15, lh = lane >> 4;
  const float* __restrict__ Xb = X + (size_t)b*NN;
  const float* __restrict__ Ab = A + (size_t)b*NN;

  float* const sT = sES;          // aliases, used only in the final phase
  float* const sS = sES + 112;

  // --- zero-init (pads must be 0 for MFMA tails) ---
  for (int i = tid; i < (112*KP)/8; i += T1) ((uint4*)sXm )[i] = uint4{0,0,0,0};
  for (int i = tid; i < (128*KP)/8; i += T1) ((uint4*)sFt )[i] = uint4{0,0,0,0};
  for (int i = tid; i < (16*KP)/8;  i += T1) ((uint4*)sF2t)[i] = uint4{0,0,0,0};
  __syncthreads();

  // --- stage Xm = X * Msig (float4 loads), adjacency ballot ---
  for (int t = tid; t < NV*28; t += T1) {
    const int n = t/28, c = t%28, k = 4*c;
    if (c < 27) {
      f32x4 x = ld4u(Xb + n*NV + k);
      f32x4 m = ld4u(Msig + n*NV + k);
      f16x4 v;
      #pragma unroll
      for (int j = 0; j < 4; ++j) v[j] = (f16)(x[j]*m[j]);
      *(f16x4*)&sXm[n*KP + k] = v;
    } else {
      sXm[n*KP + 108] = (f16)(Xb[n*NV+108]*Msig[n*NV+108]);
      sXm[n*KP + 109] = (f16)(Xb[n*NV+109]*Msig[n*NV+109]);
    }
  }
  for (int n = wave; n < NV; n += 8) {
    unsigned long long m0 = __ballot(Ab[n*NV + lane] > 0.f);
    const int mm = 64 + lane;
    unsigned long long m1 = __ballot((mm < NV) && (Ab[n*NV + mm] > 0.f));
    if (lane == 0) { sAM[2*n] = m0; sAM[2*n+1] = m1; }
  }
  // W1 B-fragments straight from global (L2-resident, zero-padded)
  f16x8 bW[4], bL[4];
  #pragma unroll
  for (int k = 0; k < 4; ++k)
    bW[k] = *(const f16x8*)&W1tg[(wave*16 + lr)*KP + k*32 + lh*8];
  if (wave == 0) {
    #pragma unroll
    for (int k = 0; k < 4; ++k)
      bL[k] = *(const f16x8*)&W1tg[(128 + lr)*KP + k*32 + lh*8];
  }
  __syncthreads();

  // --- GEMM1: feats = Xm @ W1cat ; wave w -> f-tile w ; wave0 also logits ---
  #pragma unroll
  for (int m = 0; m < 7; ++m) {
    f32x4 acc = {0.f,0.f,0.f,0.f};
    #pragma unroll
    for (int k = 0; k < 4; ++k) {
      f16x8 af = *(const f16x8*)&sXm[(m*16 + lr)*KP + k*32 + lh*8];
      acc = mfma16(af, bW[k], acc);
    }
    f16x4 v;
    #pragma unroll
    for (int r = 0; r < 4; ++r) v[r] = (f16)acc[r];
    *(f16x4*)&sFt[(wave*16 + lr)*KP + m*16 + lh*4] = v;   // sFt[f][m]
  }
  if (wave == 0) {   // logit tile: cols 128..143 -> es/en (f32)
    #pragma unroll
    for (int m = 0; m < 7; ++m) {
      f32x4 acc = {0.f,0.f,0.f,0.f};
      #pragma unroll
      for (int k = 0; k < 4; ++k) {
        f16x8 af = *(const f16x8*)&sXm[(m*16 + lr)*KP + k*32 + lh*8];
        acc = mfma16(af, bL[k], acc);
      }
      const int mg0 = m*16 + lh*4;
      if (lr < 5)       *(f32x4*)&sES[lr*112 + mg0] = acc;
      else if (lr < 10) *(f32x4*)&sEN[(lr-5)*112 + mg0] = acc;
    }
  }
  __syncthreads();

  // softmax sweep geometry: lane owns row nrow; waves split m-axis 4-ways
  const int half = wave & 1, q = wave >> 1;
  const int nrow = half*64 + lane;            // may be >= NV (inactive)
  const int m0base = q*32;
  const int nchunk = (q == 3) ? 2 : 4;        // q ranges: 32,32,32,16

  // --- 5 layer-1 head passes ---
  f16 h1r[5][2][4];
  #pragma unroll
  for (int p = 0; p < 5; ++p) {
    if (nrow < NV) {
      const float es = sES[p*112 + nrow];
      const unsigned long long am = sAM[2*nrow + (q>>1)];
      float psum = 0.f;
      for (int c = 0; c < nchunk; ++c) {
        const int m0 = m0base + c*8;
        const f32x4 enA = *(const f32x4*)&sEN[p*112 + m0];
        const f32x4 enB = *(const f32x4*)&sEN[p*112 + m0 + 4];
        const unsigned bits = (unsigned)(am >> (m0 & 63)) & 0xFFu;
        f16x8 pk;
        #pragma unroll
        for (int j = 0; j < 8; ++j) {
          float v = es + ((j < 4) ? enA[j] : enB[j-4]);
          v = fmaxf(v, LALPHA*v);                 // leaky_relu
          v = ((bits >> j) & 1u) ? v : -1e30f;    // adjacency mask
          const float e = __expf(v - 4.f);        // constant shift, norm later
          psum += e;
          pk[j] = (f16)e;
        }
        *(f16x8*)&sXm[nrow*KP + m0] = pk;
      }
      sCMB[0][nrow][q] = psum;
    }
    __syncthreads();
    // GEMM2: h_p = Pnorm @ feats_p ; normalization folded into epilogue
    const int nt = wave & 1, mh = wave >> 1;
    f16x8 bf[4];
    #pragma unroll
    for (int k = 0; k < 4; ++k)
      bf[k] = *(const f16x8*)&sFt[(p*NF1 + nt*16 + lr)*KP + k*32 + lh*8];
    const int fl = nt*16 + lr;
    const float bv = (fl < NF1) ? b1[fl] : 0.f;
    #pragma unroll
    for (int mi = 0; mi < 2; ++mi) {
      const int m = 2*mh + mi;
      if (m < 7) {
        f32x4 acc = {0.f,0.f,0.f,0.f};
        #pragma unroll
        for (int k = 0; k < 4; ++k) {
          f16x8 af = *(const f16x8*)&sXm[(m*16 + lr)*KP + k*32 + lh*8];
          acc = mfma16(af, bf[k], acc);
        }
        const int mg0 = m*16 + lh*4;
        #pragma unroll
        for (int r = 0; r < 4; ++r) {
          const f32x4 cm = *(const f32x4*)&sCMB[0][mg0 + r][0];
          const float inv = 1.f/(cm[0]+cm[1]+cm[2]+cm[3]);
          h1r[p][mi][r] = (f16)lrelu(acc[r]*inv + bv);
        }
      }
    }
    __syncthreads();
  }

  // --- dump h1 regs -> sXm[n][c] ---
  {
    const int nt = wave & 1, mh = wave >> 1, fl = nt*16 + lr;
    if (fl < NF1) {
      #pragma unroll
      for (int p = 0; p < 5; ++p) {
        #pragma unroll
        for (int mi = 0; mi < 2; ++mi) {
          const int m = 2*mh + mi;
          if (m < 7) {
            #pragma unroll
            for (int r = 0; r < 4; ++r) {
              const int mg = m*16 + lh*4 + r;
              if (mg < NV) sXm[mg*KP + p*NF1 + fl] = h1r[p][mi][r];
            }
          }
        }
      }
    }
  }
  __syncthreads();

  // --- feats2 = h1 @ W2aug : cols 0..8 feats2, cols 9..14 logits ---
  if (wave < 7) {
    f16x8 bW2[4];
    #pragma unroll
    for (int k = 0; k < 4; ++k)
      bW2[k] = *(const f16x8*)&W2tg[lr*KP + k*32 + lh*8];
    f32x4 acc = {0.f,0.f,0.f,0.f};
    #pragma unroll
    for (int k = 0; k < 4; ++k) {
      f16x8 af = *(const f16x8*)&sXm[(wave*16 + lr)*KP + k*32 + lh*8];
      acc = mfma16(af, bW2[k], acc);
    }
    const int mg0 = wave*16 + lh*4;
    if (lr < 9) {
      #pragma unroll
      for (int r = 0; r < 4; ++r) {
        const int mg = mg0 + r;
        if (mg < NV) sF2t[lr*KP + mg] = (f16)acc[r];
      }
    } else if (lr < 12) {
      *(f32x4*)&sES[(lr-9)*112 + mg0] = acc;
    } else if (lr < 15) {
      *(f32x4*)&sEN[(lr-12)*112 + mg0] = acc;
    }
  }
  __syncthreads();

  // --- 3 layer-2 head passes: sweep -> sFt, GEMM3 per-head accumulators ---
  f32x4 acc2[3];
  #pragma unroll
  for (int g = 0; g < 3; ++g) { acc2[g][0]=0.f; acc2[g][1]=0.f; acc2[g][2]=0.f; acc2[g][3]=0.f; }
  #pragma unroll
  for (int g = 0; g < 3; ++g) {
    if (nrow < NV) {
      const float es = sES[g*112 + nrow];
      const unsigned long long am = sAM[2*nrow + (q>>1)];
      float psum = 0.f;
      for (int c = 0; c < nchunk; ++c) {
        const int m0 = m0base + c*8;
        const f32x4 enA = *(const f32x4*)&sEN[g*112 + m0];
        const f32x4 enB = *(const f32x4*)&sEN[g*112 + m0 + 4];
        const unsigned bits = (unsigned)(am >> (m0 & 63)) & 0xFFu;
        f16x8 pk;
        #pragma unroll
        for (int j = 0; j < 8; ++j) {
          float v = es + ((j < 4) ? enA[j] : enB[j-4]);
          v = fmaxf(v, LALPHA*v);
          v = ((bits >> j) & 1u) ? v : -1e30f;
          const float e = __expf(v - 4.f);
          psum += e;
          pk[j] = (f16)e;
        }
        *(f16x8*)&sFt[nrow*KP + m0] = pk;
      }
      sCMB[g][nrow][q] = psum;
    }
    __syncthreads();
    if (wave < 7) {
      const int brow = (lr < NF2) ? (g*NF2 + lr) : 15;   // row 15 stays zero
      f16x8 bf2[4];
      #pragma unroll
      for (int k = 0; k < 4; ++k)
        bf2[k] = *(const f16x8*)&sF2t[brow*KP + k*32 + lh*8];
      #pragma unroll
      for (int k = 0; k < 4; ++k) {
        f16x8 af = *(const f16x8*)&sFt[(wave*16 + lr)*KP + k*32 + lh*8];
        acc2[g] = mfma16(af, bf2[k], acc2[g]);
      }
    }
    __syncthreads();
  }

  // --- t[n] = sigmoid( lrelu(mean_g(inv_g * acc2_g) + b2) . fc1 ) ---
  if (wave < 7) {
    const int mg0 = wave*16 + lh*4;
    const float fcv = (lr < NF2) ? fc1w[lr] : 0.f;
    const float b2v = (lr < NF2) ? b2[lr]  : 0.f;
    #pragma unroll
    for (int r = 0; r < 4; ++r) {
      const int mg = mg0 + r;
      float hsum = 0.f;
      #pragma unroll
      for (int g = 0; g < 3; ++g) {
        const f32x4 cm = *(const f32x4*)&sCMB[g][mg][0];
        hsum += acc2[g][r] * (1.f/(cm[0]+cm[1]+cm[2]+cm[3]));
      }
      float hv = (lr < NF2) ? lrelu(hsum*(1.f/NH2) + b2v)*fcv : 0.f;
      hv += __shfl_xor(hv, 1);
      hv += __shfl_xor(hv, 2);
      hv += __shfl_xor(hv, 4);
      hv += __shfl_xor(hv, 8);
      if (lr == 0 && mg < NV) sT[mg] = sigm(hv);
    }
  }
  __syncthreads();
  // --- s = t @ fc2 ---
  if (tid < NV) {
    float acc = 0.f;
    for (int n = 0; n < NV; ++n) acc += sT[n]*fc2w[n*NV + tid];
    sS[tid] = acc;
  }
  __syncthreads();
  // --- out[b] = sum_m t[m]*softmax(s)[m] ---
  if (wave == 0) {
    const float s0 = sS[lane];
    const float s1 = (64+lane < NV) ? sS[64+lane] : -1e38f;
    const float mx = wmax(fmaxf(s0, s1));
    const float p0 = __expf(s0 - mx);
    const float p1 = (64+lane < NV) ? __expf(s1 - mx) : 0.f;
    const float sum = wsum(p0 + p1);
    float val = sT[lane]*p0 + ((64+lane < NV) ? sT[64+lane]*p1 : 0.f);
    val = wsum(val);
    if (lane == 0) out[b] = val/sum;
  }
}

extern "C" void kernel_launch(void* const* d_in, const int* in_sizes, int n_in,
                              void* d_out, int out_size, void* d_ws, size_t ws_size,
                              hipStream_t stream) {
  const float* X   = (const float*)d_in[0];
  const float* A   = (const float*)d_in[1];
  const float* M   = (const float*)d_in[2];
  const float* W1  = (const float*)d_in[3];
  const float* as1 = (const float*)d_in[4];
  const float* an1 = (const float*)d_in[5];
  const float* b1  = (const float*)d_in[6];
  const float* W2  = (const float*)d_in[7];
  const float* as2 = (const float*)d_in[8];
  const float* an2 = (const float*)d_in[9];
  const float* b2  = (const float*)d_in[10];
  const float* fc1 = (const float*)d_in[11];
  const float* fc2 = (const float*)d_in[12];
  float* out = (float*)d_out;

  // ws: Msig f32[12100] | W1tg f16[144*136] | W2tg f16[16*136]
  float* Msig = (float*)d_ws;
  f16* W1tg = (f16*)((char*)d_ws + 48400);
  f16* W2tg = (f16*)((char*)d_ws + 48400 + W1ROWS*KP*2);

  const int pre_items = NN + W1ROWS*KP + 16*KP;
  precomp_kernel<<<(pre_items + 255)/256, 256, 0, stream>>>(
      M, W1, as1, an1, W2, as2, an2, Msig, W1tg, W2tg);
  gat_fused<<<NB, T1, 0, stream>>>(X, A, Msig, W1tg, b1, W2tg,
                                   b2, fc1, fc2, out);
}